// Round 2
// baseline (1693.551 us; speedup 1.0000x reference)
//
#include <hip/hip_runtime.h>
#include <stdint.h>

// Problem constants (fixed by the reference).
#define N_ROWS   2000000
#define DIM      128          // floats per row
#define DIM4     32           // float4 per row
#define NCLS     1000
#define DECAY    0.3f

// ---------------------------------------------------------------------------
// Pass A: per-block LDS histograms of y (unmasked) and y&mask (masked),
//         merged into global hist via one atomic per nonzero bin per block.
// NOTE: y_mask is a JAX bool -> harness passes it as int32 (4 bytes/elem).
// ---------------------------------------------------------------------------
__global__ __launch_bounds__(256) void hist_kernel(
    const int* __restrict__ y, const int* __restrict__ mask,
    int* __restrict__ hist_all, int* __restrict__ hist_m) {
  __shared__ int h_all[NCLS];
  __shared__ int h_m[NCLS];
  for (int i = threadIdx.x; i < NCLS; i += blockDim.x) { h_all[i] = 0; h_m[i] = 0; }
  __syncthreads();

  const int nvec = N_ROWS / 4;          // 500000, exact
  const int4* y4 = (const int4*)y;
  const int4* m4 = (const int4*)mask;
  for (int i = blockIdx.x * blockDim.x + threadIdx.x; i < nvec;
       i += gridDim.x * blockDim.x) {
    int4 c = y4[i];
    int4 m = m4[i];
    atomicAdd(&h_all[c.x], 1); atomicAdd(&h_all[c.y], 1);
    atomicAdd(&h_all[c.z], 1); atomicAdd(&h_all[c.w], 1);
    if (m.x) atomicAdd(&h_m[c.x], 1);
    if (m.y) atomicAdd(&h_m[c.y], 1);
    if (m.z) atomicAdd(&h_m[c.z], 1);
    if (m.w) atomicAdd(&h_m[c.w], 1);
  }
  __syncthreads();
  for (int i = threadIdx.x; i < NCLS; i += blockDim.x) {
    if (h_all[i]) atomicAdd(&hist_all[i], h_all[i]);
    if (h_m[i])   atomicAdd(&hist_m[i],   h_m[i]);
  }
}

// ---------------------------------------------------------------------------
// Pass B: exclusive prefix sum over the 1000-bin histogram (single block).
// ---------------------------------------------------------------------------
__global__ __launch_bounds__(1024) void scan_kernel(
    const int* __restrict__ hist_all, int* __restrict__ offsets,
    int* __restrict__ cursors) {
  __shared__ int buf[1024];
  int t = threadIdx.x;
  int self = (t < NCLS) ? hist_all[t] : 0;
  buf[t] = self;
  __syncthreads();
  // Hillis-Steele inclusive scan
  for (int off = 1; off < 1024; off <<= 1) {
    int v = (t >= off) ? buf[t - off] : 0;
    __syncthreads();
    buf[t] += v;
    __syncthreads();
  }
  if (t < NCLS) {
    int excl = buf[t] - self;   // inclusive -> exclusive
    offsets[t] = excl;
    cursors[t] = excl;
  }
}

// ---------------------------------------------------------------------------
// Pass C: counting-sort scatter of row indices by class.
// ---------------------------------------------------------------------------
__global__ __launch_bounds__(256) void scatter_kernel(
    const int* __restrict__ y, int* __restrict__ cursors,
    int* __restrict__ sidx) {
  int stride = gridDim.x * blockDim.x;
  for (int i = blockIdx.x * blockDim.x + threadIdx.x; i < N_ROWS; i += stride) {
    int c = y[i];
    int pos = atomicAdd(&cursors[c], 1);
    sidx[pos] = i;
  }
}

// ---------------------------------------------------------------------------
// Pass D: one block per class. 8 row-groups x 32 lanes; each lane owns one
// float4 of the row. Register accumulation (2x unroll), LDS reduce, EMA.
// ---------------------------------------------------------------------------
__global__ __launch_bounds__(256) void reduce_kernel(
    const float* __restrict__ x, const int* __restrict__ mask,
    const int* __restrict__ sidx, const int* __restrict__ offsets,
    const int* __restrict__ hist_all, const int* __restrict__ hist_m,
    const float* __restrict__ centroids, float* __restrict__ out) {
  const int cls  = blockIdx.x;
  const int beg  = offsets[cls];
  const int cnt  = hist_all[cls];
  const int g    = threadIdx.x >> 5;    // row group 0..7
  const int lane = threadIdx.x & 31;    // float4 column 0..31
  const float4* x4 = (const float4*)x;

  float4 acc = make_float4(0.f, 0.f, 0.f, 0.f);
  int i = g;
  for (; i + 8 < cnt; i += 16) {
    int row0 = sidx[beg + i];
    int row1 = sidx[beg + i + 8];
    float m0 = mask[row0] ? 1.0f : 0.0f;
    float m1 = mask[row1] ? 1.0f : 0.0f;
    float4 v0 = x4[row0 * DIM4 + lane];
    float4 v1 = x4[row1 * DIM4 + lane];
    acc.x += m0 * v0.x + m1 * v1.x;
    acc.y += m0 * v0.y + m1 * v1.y;
    acc.z += m0 * v0.z + m1 * v1.z;
    acc.w += m0 * v0.w + m1 * v1.w;
  }
  for (; i < cnt; i += 8) {
    int row = sidx[beg + i];
    float m = mask[row] ? 1.0f : 0.0f;
    float4 v = x4[row * DIM4 + lane];
    acc.x += m * v.x; acc.y += m * v.y;
    acc.z += m * v.z; acc.w += m * v.w;
  }

  __shared__ float4 red[256];
  red[threadIdx.x] = acc;
  __syncthreads();

  if (threadIdx.x < 32) {
    float4 s = red[lane];
    #pragma unroll
    for (int gg = 1; gg < 8; ++gg) {
      float4 v = red[gg * 32 + lane];
      s.x += v.x; s.y += v.y; s.z += v.z; s.w += v.w;
    }
    float cm  = fmaxf((float)hist_m[cls], 1.0f);
    float inv = 1.0f / cm;
    float4 cent = ((const float4*)centroids)[cls * DIM4 + lane];
    float4 o;
    if (cnt > 0) {   // class present in y (unmasked), per reference
      o.x = DECAY * (s.x * inv) + (1.0f - DECAY) * cent.x;
      o.y = DECAY * (s.y * inv) + (1.0f - DECAY) * cent.y;
      o.z = DECAY * (s.z * inv) + (1.0f - DECAY) * cent.z;
      o.w = DECAY * (s.w * inv) + (1.0f - DECAY) * cent.w;
    } else {
      o = cent;
    }
    ((float4*)out)[cls * DIM4 + lane] = o;
  }
}

// ---------------------------------------------------------------------------
// Fallback (small ws): direct atomic accumulation. ~256M atomics, slow but
// correct; only used if ws can't hold the 8 MB sorted-index buffer.
// ---------------------------------------------------------------------------
__global__ __launch_bounds__(256) void fb_accum_kernel(
    const float* __restrict__ x, const int* __restrict__ y,
    const int* __restrict__ mask, float* __restrict__ sums) {
  const long total = (long)N_ROWS * DIM4;
  const float4* x4 = (const float4*)x;
  for (long idx = (long)blockIdx.x * blockDim.x + threadIdx.x; idx < total;
       idx += (long)gridDim.x * blockDim.x) {
    int row  = (int)(idx >> 5);
    int lane = (int)(idx & 31);
    if (mask[row]) {
      int c = y[row];
      float4 v = x4[idx];
      atomicAdd(&sums[c * DIM + lane * 4 + 0], v.x);
      atomicAdd(&sums[c * DIM + lane * 4 + 1], v.y);
      atomicAdd(&sums[c * DIM + lane * 4 + 2], v.z);
      atomicAdd(&sums[c * DIM + lane * 4 + 3], v.w);
    }
  }
}

__global__ __launch_bounds__(32) void fb_final_kernel(
    const float* __restrict__ sums, const int* __restrict__ hist_all,
    const int* __restrict__ hist_m, const float* __restrict__ centroids,
    float* __restrict__ out) {
  int cls = blockIdx.x;
  int lane = threadIdx.x;
  float4 s = ((const float4*)sums)[cls * DIM4 + lane];
  float cm = fmaxf((float)hist_m[cls], 1.0f);
  float inv = 1.0f / cm;
  float4 cent = ((const float4*)centroids)[cls * DIM4 + lane];
  float4 o;
  if (hist_all[cls] > 0) {
    o.x = DECAY * (s.x * inv) + (1.0f - DECAY) * cent.x;
    o.y = DECAY * (s.y * inv) + (1.0f - DECAY) * cent.y;
    o.z = DECAY * (s.z * inv) + (1.0f - DECAY) * cent.z;
    o.w = DECAY * (s.w * inv) + (1.0f - DECAY) * cent.w;
  } else {
    o = cent;
  }
  ((float4*)out)[cls * DIM4 + lane] = o;
}

// ---------------------------------------------------------------------------
extern "C" void kernel_launch(void* const* d_in, const int* in_sizes, int n_in,
                              void* d_out, int out_size, void* d_ws,
                              size_t ws_size, hipStream_t stream) {
  const float* x    = (const float*)d_in[0];
  const int*   y    = (const int*)d_in[1];
  const int*   mask = (const int*)d_in[2];   // jax bool -> int32 on harness side
  const float* cent = (const float*)d_in[3];
  float*       out  = (float*)d_out;

  char* ws = (char*)d_ws;
  // Sort-path layout
  int* hist_all = (int*)(ws + 0);
  int* hist_m   = (int*)(ws + 4000);
  int* offsets  = (int*)(ws + 8000);
  int* cursors  = (int*)(ws + 12000);
  int* sidx     = (int*)(ws + 16000);
  const size_t sort_need = 16000 + (size_t)N_ROWS * 4;

  if (ws_size >= sort_need) {
    // zero histograms (ws is poisoned 0xAA before every call)
    hipMemsetAsync(ws, 0, 8000, stream);
    hist_kernel<<<256, 256, 0, stream>>>(y, mask, hist_all, hist_m);
    scan_kernel<<<1, 1024, 0, stream>>>(hist_all, offsets, cursors);
    scatter_kernel<<<1024, 256, 0, stream>>>(y, cursors, sidx);
    reduce_kernel<<<NCLS, 256, 0, stream>>>(x, mask, sidx, offsets, hist_all,
                                            hist_m, cent, out);
  } else {
    // Fallback layout: hist_all@0, hist_m@4000, sums@8000 (512 KB)
    float* sums = (float*)(ws + 8000);
    hipMemsetAsync(ws, 0, 8000 + (size_t)NCLS * DIM * sizeof(float), stream);
    hist_kernel<<<256, 256, 0, stream>>>(y, mask, hist_all, hist_m);
    fb_accum_kernel<<<8192, 256, 0, stream>>>(x, y, mask, sums);
    fb_final_kernel<<<NCLS, 32, 0, stream>>>(sums, hist_all, hist_m, cent, out);
  }
}